// Round 1
// baseline (1173.525 us; speedup 1.0000x reference)
//
#include <hip/hip_runtime.h>
#include <hip/hip_bf16.h>
#include <stdint.h>

typedef _Float16 f16;
typedef __attribute__((ext_vector_type(8))) _Float16 half8;
typedef __attribute__((ext_vector_type(4))) _Float16 half4;
typedef __attribute__((ext_vector_type(4))) float f32x4;

// ---------------------------------------------------------------------------
// P1: transpose + cast x [8,4096,256] f32 -> xT [8,256,4096] f16
// grid (64, 4, 8), block 256
// ---------------------------------------------------------------------------
__global__ void __launch_bounds__(256) transpose_x_kernel(
    const float* __restrict__ x, f16* __restrict__ xT)
{
    __shared__ __align__(16) f16 tile[64][72];  // row = 144B = 9*16B, 16B-aligned slices
    int b  = blockIdx.z;
    int m0 = blockIdx.x * 64;
    int d0 = blockIdx.y * 64;
    const float* xb = x + (size_t)b * 4096 * 256;
    f16* xTb = xT + (size_t)b * 256 * 4096;
    int tid = threadIdx.x;
    int c4 = tid & 15;      // float4 slot in a 64-float row
    int rb = tid >> 4;      // 0..15
#pragma unroll
    for (int p = 0; p < 4; ++p) {
        int row = p * 16 + rb;  // 0..63
        float4 v = *(const float4*)(xb + (size_t)(m0 + row) * 256 + d0 + c4 * 4);
        tile[c4 * 4 + 0][row] = (f16)v.x;
        tile[c4 * 4 + 1][row] = (f16)v.y;
        tile[c4 * 4 + 2][row] = (f16)v.z;
        tile[c4 * 4 + 3][row] = (f16)v.w;
    }
    __syncthreads();
    int mseg = tid & 7;
    int db = tid >> 3;      // 0..31
#pragma unroll
    for (int p = 0; p < 2; ++p) {
        int dd = p * 32 + db;
        uint4 val = *(const uint4*)&tile[dd][mseg * 8];
        *(uint4*)(xTb + (size_t)(d0 + dd) * 4096 + m0 + mseg * 8) = val;
    }
}

// ---------------------------------------------------------------------------
// P2: W1 [256,512] -> W1T [512,256] f16 ; W2 [512,256] -> W2T [256,512] f16
// grid 1024, block 256
// ---------------------------------------------------------------------------
__global__ void __launch_bounds__(256) prep_weights_kernel(
    const float* __restrict__ W1, const float* __restrict__ W2,
    f16* __restrict__ W1T, f16* __restrict__ W2T)
{
    int idx = blockIdx.x * 256 + threadIdx.x;   // 0 .. 262143
    if (idx < 131072) {
        int n = idx >> 8;     // 0..511
        int k = idx & 255;    // 0..255
        W1T[idx] = (f16)W1[k * 512 + n];
    } else {
        int j = idx - 131072;
        int d = j >> 9;       // 0..255
        int h = j & 511;      // 0..511
        W2T[j] = (f16)W2[h * 256 + d];
    }
}

// ---------------------------------------------------------------------------
// K1: per-batch C = adj @ x via MFMA f16 (fp32 accum), fused (1+eps)*x + C -> h (f16)
// BM=64, BN=256 (full width), BK=32. Block 256 (4 waves, 2x2), wave tile 32x128.
// grid (64, 8), block 256
// ---------------------------------------------------------------------------
__global__ void __launch_bounds__(256) bmm_kernel(
    const float* __restrict__ adj, const f16* __restrict__ xT,
    const float* __restrict__ x, const float* __restrict__ eps,
    f16* __restrict__ h)
{
    __shared__ __align__(16) f16 As[64][40];    // +8 pad breaks bank conflicts
    __shared__ __align__(16) f16 Bs[256][40];

    int b   = blockIdx.y;
    int m0  = blockIdx.x * 64;
    int tid = threadIdx.x;
    int lane = tid & 63;
    int wid  = tid >> 6;
    int wm = (wid & 1) * 32;     // wave row offset
    int wn = (wid >> 1) * 128;   // wave col offset
    int l15 = lane & 15;
    int lg  = lane >> 4;         // 0..3

    const float* adjb = adj + (size_t)b * 4096 * 4096;
    const f16*   xTb  = xT  + (size_t)b * 256 * 4096;

    // staging coords: A tile 64x32 f32 (8 lanes/row of float4), B tile 256x32 f16
    int ar = tid >> 3;   // 0..31 (+p*32)
    int ac = tid & 7;    // float4 slot
    int br = tid >> 2;   // 0..63 (+p*64)
    int bc = tid & 3;    // 8-f16 slot

    f32x4 acc[2][8];
#pragma unroll
    for (int i = 0; i < 2; ++i)
#pragma unroll
        for (int j = 0; j < 8; ++j) { f32x4 z = {0.f, 0.f, 0.f, 0.f}; acc[i][j] = z; }

    float4 aR[2];
    uint4  bR[4];
    // preload kk = 0
#pragma unroll
    for (int p = 0; p < 2; ++p)
        aR[p] = *(const float4*)(adjb + (size_t)(m0 + p * 32 + ar) * 4096 + ac * 4);
#pragma unroll
    for (int p = 0; p < 4; ++p)
        bR[p] = *(const uint4*)(xTb + (size_t)(p * 64 + br) * 4096 + bc * 8);

    for (int kk = 0; kk < 4096; kk += 32) {
        // stage prefetched regs -> LDS (f32 -> f16 convert for A)
#pragma unroll
        for (int p = 0; p < 2; ++p) {
            half4 t;
            t.x = (f16)aR[p].x; t.y = (f16)aR[p].y; t.z = (f16)aR[p].z; t.w = (f16)aR[p].w;
            *(half4*)&As[p * 32 + ar][ac * 4] = t;
        }
#pragma unroll
        for (int p = 0; p < 4; ++p)
            *(uint4*)&Bs[p * 64 + br][bc * 8] = bR[p];
        __syncthreads();

        // prefetch next k-tile while this one computes
        int kn = kk + 32;
        if (kn < 4096) {
#pragma unroll
            for (int p = 0; p < 2; ++p)
                aR[p] = *(const float4*)(adjb + (size_t)(m0 + p * 32 + ar) * 4096 + kn + ac * 4);
#pragma unroll
            for (int p = 0; p < 4; ++p)
                bR[p] = *(const uint4*)(xTb + (size_t)(p * 64 + br) * 4096 + kn + bc * 8);
        }

        half8 af[2], bfr[8];
#pragma unroll
        for (int mt = 0; mt < 2; ++mt)
            af[mt] = *(const half8*)&As[wm + mt * 16 + l15][lg * 8];
#pragma unroll
        for (int nt = 0; nt < 8; ++nt)
            bfr[nt] = *(const half8*)&Bs[wn + nt * 16 + l15][lg * 8];
#pragma unroll
        for (int mt = 0; mt < 2; ++mt)
#pragma unroll
            for (int nt = 0; nt < 8; ++nt)
                acc[mt][nt] = __builtin_amdgcn_mfma_f32_16x16x32_f16(af[mt], bfr[nt], acc[mt][nt], 0, 0, 0);
        __syncthreads();
    }

    // epilogue: h = (1+eps)*x + acc   (C/D layout: col = lane&15, row = lg*4 + i)
    float scale = 1.0f + eps[0];
    const float* xb = x + (size_t)b * 4096 * 256;
    f16* hb = h + (size_t)b * 4096 * 256;
#pragma unroll
    for (int mt = 0; mt < 2; ++mt) {
#pragma unroll
        for (int i = 0; i < 4; ++i) {
            int row = m0 + wm + mt * 16 + lg * 4 + i;
#pragma unroll
            for (int nt = 0; nt < 8; ++nt) {
                int col = wn + nt * 16 + l15;
                float hv = scale * xb[(size_t)row * 256 + col] + acc[mt][nt][i];
                hb[(size_t)row * 256 + col] = (f16)hv;
            }
        }
    }
}

// ---------------------------------------------------------------------------
// K2: hidden = relu(h @ W1 + b1).  M=32768, N=512, K=256.
// BM=128, BN=128, BK=32. Wave tile 64x64. grid (256, 4), block 256
// ---------------------------------------------------------------------------
__global__ void __launch_bounds__(256) mlp1_kernel(
    const f16* __restrict__ h, const f16* __restrict__ W1T,
    const float* __restrict__ b1, f16* __restrict__ hidden)
{
    __shared__ __align__(16) f16 As[128][40];
    __shared__ __align__(16) f16 Bs[128][40];

    int m0 = blockIdx.x * 128;
    int n0 = blockIdx.y * 128;
    int tid = threadIdx.x;
    int lane = tid & 63;
    int wid  = tid >> 6;
    int wm = (wid & 1) * 64;
    int wn = (wid >> 1) * 64;
    int l15 = lane & 15;
    int lg  = lane >> 4;
    int r = tid >> 2;   // 0..63 (+p*64)
    int c = tid & 3;    // 8-f16 slot

    f32x4 acc[4][4];
#pragma unroll
    for (int i = 0; i < 4; ++i)
#pragma unroll
        for (int j = 0; j < 4; ++j) { f32x4 z = {0.f, 0.f, 0.f, 0.f}; acc[i][j] = z; }

    uint4 aR[2], bR[2];
#pragma unroll
    for (int p = 0; p < 2; ++p) {
        aR[p] = *(const uint4*)(h   + (size_t)(m0 + p * 64 + r) * 256 + c * 8);
        bR[p] = *(const uint4*)(W1T + (size_t)(n0 + p * 64 + r) * 256 + c * 8);
    }

    for (int kk = 0; kk < 256; kk += 32) {
#pragma unroll
        for (int p = 0; p < 2; ++p) {
            *(uint4*)&As[p * 64 + r][c * 8] = aR[p];
            *(uint4*)&Bs[p * 64 + r][c * 8] = bR[p];
        }
        __syncthreads();
        int kn = kk + 32;
        if (kn < 256) {
#pragma unroll
            for (int p = 0; p < 2; ++p) {
                aR[p] = *(const uint4*)(h   + (size_t)(m0 + p * 64 + r) * 256 + kn + c * 8);
                bR[p] = *(const uint4*)(W1T + (size_t)(n0 + p * 64 + r) * 256 + kn + c * 8);
            }
        }
        half8 af[4], bfr[4];
#pragma unroll
        for (int mt = 0; mt < 4; ++mt)
            af[mt] = *(const half8*)&As[wm + mt * 16 + l15][lg * 8];
#pragma unroll
        for (int nt = 0; nt < 4; ++nt)
            bfr[nt] = *(const half8*)&Bs[wn + nt * 16 + l15][lg * 8];
#pragma unroll
        for (int mt = 0; mt < 4; ++mt)
#pragma unroll
            for (int nt = 0; nt < 4; ++nt)
                acc[mt][nt] = __builtin_amdgcn_mfma_f32_16x16x32_f16(af[mt], bfr[nt], acc[mt][nt], 0, 0, 0);
        __syncthreads();
    }

#pragma unroll
    for (int mt = 0; mt < 4; ++mt) {
#pragma unroll
        for (int i = 0; i < 4; ++i) {
            int row = m0 + wm + mt * 16 + lg * 4 + i;
#pragma unroll
            for (int nt = 0; nt < 4; ++nt) {
                int col = n0 + wn + nt * 16 + l15;
                float v = acc[mt][nt][i] + b1[col];
                v = v > 0.f ? v : 0.f;
                hidden[(size_t)row * 512 + col] = (f16)v;
            }
        }
    }
}

// ---------------------------------------------------------------------------
// K3: out = hidden @ W2 + b2.  M=32768, N=256, K=512.
// BM=128, BN=128, BK=32. grid (256, 2), block 256
// ---------------------------------------------------------------------------
__global__ void __launch_bounds__(256) mlp2_kernel(
    const f16* __restrict__ hidden, const f16* __restrict__ W2T,
    const float* __restrict__ b2, float* __restrict__ out)
{
    __shared__ __align__(16) f16 As[128][40];
    __shared__ __align__(16) f16 Bs[128][40];

    int m0 = blockIdx.x * 128;
    int n0 = blockIdx.y * 128;
    int tid = threadIdx.x;
    int lane = tid & 63;
    int wid  = tid >> 6;
    int wm = (wid & 1) * 64;
    int wn = (wid >> 1) * 64;
    int l15 = lane & 15;
    int lg  = lane >> 4;
    int r = tid >> 2;
    int c = tid & 3;

    f32x4 acc[4][4];
#pragma unroll
    for (int i = 0; i < 4; ++i)
#pragma unroll
        for (int j = 0; j < 4; ++j) { f32x4 z = {0.f, 0.f, 0.f, 0.f}; acc[i][j] = z; }

    uint4 aR[2], bR[2];
#pragma unroll
    for (int p = 0; p < 2; ++p) {
        aR[p] = *(const uint4*)(hidden + (size_t)(m0 + p * 64 + r) * 512 + c * 8);
        bR[p] = *(const uint4*)(W2T    + (size_t)(n0 + p * 64 + r) * 512 + c * 8);
    }

    for (int kk = 0; kk < 512; kk += 32) {
#pragma unroll
        for (int p = 0; p < 2; ++p) {
            *(uint4*)&As[p * 64 + r][c * 8] = aR[p];
            *(uint4*)&Bs[p * 64 + r][c * 8] = bR[p];
        }
        __syncthreads();
        int kn = kk + 32;
        if (kn < 512) {
#pragma unroll
            for (int p = 0; p < 2; ++p) {
                aR[p] = *(const uint4*)(hidden + (size_t)(m0 + p * 64 + r) * 512 + kn + c * 8);
                bR[p] = *(const uint4*)(W2T    + (size_t)(n0 + p * 64 + r) * 512 + kn + c * 8);
            }
        }
        half8 af[4], bfr[4];
#pragma unroll
        for (int mt = 0; mt < 4; ++mt)
            af[mt] = *(const half8*)&As[wm + mt * 16 + l15][lg * 8];
#pragma unroll
        for (int nt = 0; nt < 4; ++nt)
            bfr[nt] = *(const half8*)&Bs[wn + nt * 16 + l15][lg * 8];
#pragma unroll
        for (int mt = 0; mt < 4; ++mt)
#pragma unroll
            for (int nt = 0; nt < 4; ++nt)
                acc[mt][nt] = __builtin_amdgcn_mfma_f32_16x16x32_f16(af[mt], bfr[nt], acc[mt][nt], 0, 0, 0);
        __syncthreads();
    }

#pragma unroll
    for (int mt = 0; mt < 4; ++mt) {
#pragma unroll
        for (int i = 0; i < 4; ++i) {
            int row = m0 + wm + mt * 16 + lg * 4 + i;
#pragma unroll
            for (int nt = 0; nt < 4; ++nt) {
                int col = n0 + wn + nt * 16 + l15;
                out[(size_t)row * 256 + col] = acc[mt][nt][i] + b2[col];
            }
        }
    }
}

// ---------------------------------------------------------------------------
// launch
// ---------------------------------------------------------------------------
extern "C" void kernel_launch(void* const* d_in, const int* in_sizes, int n_in,
                              void* d_out, int out_size, void* d_ws, size_t ws_size,
                              hipStream_t stream) {
    (void)in_sizes; (void)n_in; (void)out_size; (void)ws_size;
    const float* x   = (const float*)d_in[0];
    const float* adj = (const float*)d_in[1];
    const float* eps = (const float*)d_in[2];
    const float* W1  = (const float*)d_in[3];
    const float* b1  = (const float*)d_in[4];
    const float* W2  = (const float*)d_in[5];
    const float* b2  = (const float*)d_in[6];
    float* out = (float*)d_out;

    char* ws = (char*)d_ws;
    // ws layout (49 MiB total):
    //   [0,        16 MiB) : h_f16     [32768, 256]
    //   [16 MiB,   32 MiB) : xT_f16    [8, 256, 4096]  (consumed by bmm, then
    //   [16 MiB,   48 MiB) : hidden_f16[32768, 512]     overwritten by mlp1 — stream-ordered, safe)
    //   [48 MiB,  +512KiB) : W1T_f16   [512, 256]
    //   [+512KiB, +512KiB) : W2T_f16   [256, 512]
    f16* h_f16   = (f16*)(ws);
    f16* xT      = (f16*)(ws + (16u << 20));
    f16* hidden  = (f16*)(ws + (16u << 20));
    f16* W1T     = (f16*)(ws + (48u << 20));
    f16* W2T     = (f16*)(ws + (48u << 20) + 131072u * 2u * 2u);

    transpose_x_kernel<<<dim3(64, 4, 8), dim3(256), 0, stream>>>(x, xT);
    prep_weights_kernel<<<dim3(1024), dim3(256), 0, stream>>>(W1, W2, W1T, W2T);
    bmm_kernel<<<dim3(64, 8), dim3(256), 0, stream>>>(adj, xT, x, eps, h_f16);
    mlp1_kernel<<<dim3(256, 4), dim3(256), 0, stream>>>(h_f16, W1T, b1, hidden);
    mlp2_kernel<<<dim3(256, 2), dim3(256), 0, stream>>>(hidden, W2T, b2, out);
}

// Round 2
// 870.548 us; speedup vs baseline: 1.3480x; 1.3480x over previous
//
#include <hip/hip_runtime.h>
#include <hip/hip_bf16.h>
#include <stdint.h>

typedef _Float16 f16;
typedef __attribute__((ext_vector_type(8))) _Float16 half8;
typedef __attribute__((ext_vector_type(4))) float f32x4;

typedef __attribute__((address_space(1))) void gvoid_t;
typedef __attribute__((address_space(3))) void lvoid_t;

// HBM -> LDS DMA, 16 B per lane. LDS dest is wave-uniform base + lane*16.
__device__ __forceinline__ void dma16(const void* g, void* l) {
    __builtin_amdgcn_global_load_lds((gvoid_t*)g, (lvoid_t*)l, 16, 0, 0);
}

// ---------------------------------------------------------------------------
// P1: transpose + cast x [8,4096,256] f32 -> xT [8,256,4096] f16
// grid (64, 4, 8), block 256
// ---------------------------------------------------------------------------
__global__ void __launch_bounds__(256) transpose_x_kernel(
    const float* __restrict__ x, f16* __restrict__ xT)
{
    __shared__ __align__(16) f16 tile[64][72];
    int b  = blockIdx.z;
    int m0 = blockIdx.x * 64;
    int d0 = blockIdx.y * 64;
    const float* xb = x + (size_t)b * 4096 * 256;
    f16* xTb = xT + (size_t)b * 256 * 4096;
    int tid = threadIdx.x;
    int c4 = tid & 15;
    int rb = tid >> 4;
#pragma unroll
    for (int p = 0; p < 4; ++p) {
        int row = p * 16 + rb;
        float4 v = *(const float4*)(xb + (size_t)(m0 + row) * 256 + d0 + c4 * 4);
        tile[c4 * 4 + 0][row] = (f16)v.x;
        tile[c4 * 4 + 1][row] = (f16)v.y;
        tile[c4 * 4 + 2][row] = (f16)v.z;
        tile[c4 * 4 + 3][row] = (f16)v.w;
    }
    __syncthreads();
    int mseg = tid & 7;
    int db = tid >> 3;
#pragma unroll
    for (int p = 0; p < 2; ++p) {
        int dd = p * 32 + db;
        uint4 val = *(const uint4*)&tile[dd][mseg * 8];
        *(uint4*)(xTb + (size_t)(d0 + dd) * 4096 + m0 + mseg * 8) = val;
    }
}

// ---------------------------------------------------------------------------
// P2: weight transposes to n-major f16
// ---------------------------------------------------------------------------
__global__ void __launch_bounds__(256) prep_weights_kernel(
    const float* __restrict__ W1, const float* __restrict__ W2,
    f16* __restrict__ W1T, f16* __restrict__ W2T)
{
    int idx = blockIdx.x * 256 + threadIdx.x;
    if (idx < 131072) {
        int n = idx >> 8;
        int k = idx & 255;
        W1T[idx] = (f16)W1[k * 512 + n];
    } else {
        int j = idx - 131072;
        int d = j >> 9;
        int hh = j & 511;
        W2T[j] = (f16)W2[hh * 256 + d];
    }
}

// ---------------------------------------------------------------------------
// K1: h = (1+eps)*x + adj @ x   (per batch), f16 MFMA, fp32 accum.
// BM=64, BN=256 (full d), BK=32. 4 waves (2x2), wave tile 32x128.
// One barrier per K-iter; double-buffered LDS filled by global_load_lds DMA.
// A kept fp32 in LDS (DMA can't convert); cvt at frag read.
// XOR-swizzled unpadded layouts -> DMA-compatible AND ~conflict-free reads.
// grid (64, 8), block 256
// ---------------------------------------------------------------------------
__device__ __forceinline__ void bmm_dma_tile(
    const float* adjb, const f16* xTb, float* AsBuf, f16* BsBuf,
    int kk, int wid, int lane)
{
    // A tile: 64 rows x 32 f32 (8 KB) = 8 chunks of 8 rows; wave w: chunks w, w+4
    int a_rr = lane >> 3, a_sl = lane & 7;
#pragma unroll
    for (int c = 0; c < 2; ++c) {
        int chunk = wid + c * 4;
        int r = chunk * 8 + a_rr;
        int colg = a_sl ^ ((r & 7) ^ ((r >> 3) & 1));   // swizzle slot of 4 floats
        dma16(adjb + (size_t)r * 4096 + kk + colg * 4, AsBuf + chunk * 256);
    }
    // B tile: 256 rows x 32 f16 (16 KB) = 16 chunks of 16 rows; wave w: w,w+4,w+8,w+12
    int b_rr = lane >> 2, b_sl = lane & 3;
#pragma unroll
    for (int c = 0; c < 4; ++c) {
        int chunk = wid + c * 4;
        int r = chunk * 16 + b_rr;
        int colg = b_sl ^ ((r & 3) ^ ((r >> 2) & 3));   // swizzle slot of 8 f16
        dma16(xTb + (size_t)r * 4096 + kk + colg * 8, BsBuf + chunk * 512);
    }
}

__global__ void __launch_bounds__(256) bmm_kernel(
    const float* __restrict__ adj, const f16* __restrict__ xT,
    const float* __restrict__ x, const float* __restrict__ eps,
    f16* __restrict__ h)
{
    __shared__ __align__(16) float As[2][64 * 32];   // 2 x 8 KB
    __shared__ __align__(16) f16  Bs[2][256 * 32];   // 2 x 16 KB

    const int b   = blockIdx.y;
    const int m0  = blockIdx.x * 64;
    const int tid = threadIdx.x;
    const int lane = tid & 63, wid = tid >> 6;
    const int wm = (wid & 1) * 32;
    const int wn = (wid >> 1) * 128;
    const int l15 = lane & 15, lg = lane >> 4;

    const float* adjb = adj + (size_t)b * 4096 * 4096 + (size_t)m0 * 4096;
    const f16*   xTb  = xT  + (size_t)b * 256 * 4096;

    f32x4 acc[2][8];
#pragma unroll
    for (int i = 0; i < 2; ++i)
#pragma unroll
        for (int j = 0; j < 8; ++j) { f32x4 z = {0.f, 0.f, 0.f, 0.f}; acc[i][j] = z; }

    // prologue: DMA tile 0 into buf 0
    bmm_dma_tile(adjb, xTb, As[0], Bs[0], 0, wid, lane);

    // frag-read swizzle factors (depend only on l15; tile bases are x16 aligned)
    const int sA = (l15 & 7) ^ (l15 >> 3);
    const int sB = (l15 & 3) ^ ((l15 >> 2) & 3);

    for (int it = 0; it < 128; ++it) {
        const int buf = it & 1;
        __syncthreads();                 // drains prev-iter DMA (vmcnt) + frag reads
        if (it + 1 < 128)
            bmm_dma_tile(adjb, xTb, As[buf ^ 1], Bs[buf ^ 1], (it + 1) * 32, wid, lane);

        const float* Ab = As[buf];
        const f16*  Bb  = Bs[buf];
        half8 af[2];
#pragma unroll
        for (int mt = 0; mt < 2; ++mt) {
            int R = wm + mt * 16 + l15;
            int p0 = (2 * lg) ^ sA;
            f32x4 a0 = *(const f32x4*)&Ab[R * 32 + p0 * 4];
            f32x4 a1 = *(const f32x4*)&Ab[R * 32 + (p0 ^ 1) * 4];
            half8 t;
            t[0] = (f16)a0.x; t[1] = (f16)a0.y; t[2] = (f16)a0.z; t[3] = (f16)a0.w;
            t[4] = (f16)a1.x; t[5] = (f16)a1.y; t[6] = (f16)a1.z; t[7] = (f16)a1.w;
            af[mt] = t;
        }
        half8 bfr[8];
        const int slotB = lg ^ sB;
#pragma unroll
        for (int nt = 0; nt < 8; ++nt) {
            int C = wn + nt * 16 + l15;
            bfr[nt] = *(const half8*)&Bb[C * 32 + slotB * 8];
        }
#pragma unroll
        for (int mt = 0; mt < 2; ++mt)
#pragma unroll
            for (int nt = 0; nt < 8; ++nt)
                acc[mt][nt] = __builtin_amdgcn_mfma_f32_16x16x32_f16(af[mt], bfr[nt], acc[mt][nt], 0, 0, 0);
    }

    // epilogue: h = (1+eps)*x + acc   (C/D: col = l15, row = lg*4 + i)
    float scale = 1.0f + eps[0];
    const float* xb = x + (size_t)b * 4096 * 256;
    f16* hb = h + (size_t)b * 4096 * 256;
#pragma unroll
    for (int mt = 0; mt < 2; ++mt) {
#pragma unroll
        for (int i = 0; i < 4; ++i) {
            int row = m0 + wm + mt * 16 + lg * 4 + i;
#pragma unroll
            for (int nt = 0; nt < 8; ++nt) {
                int col = wn + nt * 16 + l15;
                float hv = scale * xb[(size_t)row * 256 + col] + acc[mt][nt][i];
                hb[(size_t)row * 256 + col] = (f16)hv;
            }
        }
    }
}

// ---------------------------------------------------------------------------
// K2/K3: C = act(A @ BT^T + bias). A [M,K] f16, BT [N,K] f16.
// BM=128, BN=128, BK=32, 4 waves (2x2), wave tile 64x64.
// Same one-barrier DMA double-buffer structure.
// ---------------------------------------------------------------------------
__device__ __forceinline__ void mlp_dma_tile(
    const f16* Am, const f16* Bn, f16* AsBuf, f16* BsBuf,
    int kk, int K, int wid, int lane)
{
    // each tile: 128 rows x 32 f16 (8 KB) = 8 chunks of 16 rows; wave w: w, w+4
    int rr = lane >> 2, sl = lane & 3;
#pragma unroll
    for (int c = 0; c < 2; ++c) {
        int chunk = wid + c * 4;
        int r = chunk * 16 + rr;
        int colg = sl ^ ((r & 3) ^ ((r >> 2) & 3));
        dma16(Am + (size_t)r * K + kk + colg * 8, AsBuf + chunk * 512);
        dma16(Bn + (size_t)r * K + kk + colg * 8, BsBuf + chunk * 512);
    }
}

template <int K, bool RELU, bool OUTF32>
__global__ void __launch_bounds__(256) mlp_kernel(
    const f16* __restrict__ A, const f16* __restrict__ BT,
    const float* __restrict__ bias, void* __restrict__ outv, int Ntot)
{
    __shared__ __align__(16) f16 As[2][128 * 32];   // 2 x 8 KB
    __shared__ __align__(16) f16 Bs[2][128 * 32];

    const int m0 = blockIdx.x * 128;
    const int n0 = blockIdx.y * 128;
    const int tid = threadIdx.x;
    const int lane = tid & 63, wid = tid >> 6;
    const int wm = (wid & 1) * 64;
    const int wn = (wid >> 1) * 64;
    const int l15 = lane & 15, lg = lane >> 4;

    const f16* Am = A  + (size_t)m0 * K;
    const f16* Bn = BT + (size_t)n0 * K;

    f32x4 acc[4][4];
#pragma unroll
    for (int i = 0; i < 4; ++i)
#pragma unroll
        for (int j = 0; j < 4; ++j) { f32x4 z = {0.f, 0.f, 0.f, 0.f}; acc[i][j] = z; }

    mlp_dma_tile(Am, Bn, As[0], Bs[0], 0, K, wid, lane);

    const int sf = (l15 & 3) ^ ((l15 >> 2) & 3);
    const int slot = lg ^ sf;
    const int NIT = K / 32;

    for (int it = 0; it < NIT; ++it) {
        const int buf = it & 1;
        __syncthreads();
        if (it + 1 < NIT)
            mlp_dma_tile(Am, Bn, As[buf ^ 1], Bs[buf ^ 1], (it + 1) * 32, K, wid, lane);

        half8 af[4], bf[4];
#pragma unroll
        for (int mt = 0; mt < 4; ++mt) {
            int R = wm + mt * 16 + l15;
            af[mt] = *(const half8*)&As[buf][R * 32 + slot * 8];
        }
#pragma unroll
        for (int nt = 0; nt < 4; ++nt) {
            int C = wn + nt * 16 + l15;
            bf[nt] = *(const half8*)&Bs[buf][C * 32 + slot * 8];
        }
#pragma unroll
        for (int mt = 0; mt < 4; ++mt)
#pragma unroll
            for (int nt = 0; nt < 4; ++nt)
                acc[mt][nt] = __builtin_amdgcn_mfma_f32_16x16x32_f16(af[mt], bf[nt], acc[mt][nt], 0, 0, 0);
    }

#pragma unroll
    for (int mt = 0; mt < 4; ++mt) {
#pragma unroll
        for (int i = 0; i < 4; ++i) {
            int row = m0 + wm + mt * 16 + lg * 4 + i;
#pragma unroll
            for (int nt = 0; nt < 4; ++nt) {
                int col = n0 + wn + nt * 16 + l15;
                float v = acc[mt][nt][i] + bias[col];
                if (RELU) v = v > 0.f ? v : 0.f;
                if (OUTF32)
                    ((float*)outv)[(size_t)row * Ntot + col] = v;
                else
                    ((f16*)outv)[(size_t)row * Ntot + col] = (f16)v;
            }
        }
    }
}

// ---------------------------------------------------------------------------
// launch
// ---------------------------------------------------------------------------
extern "C" void kernel_launch(void* const* d_in, const int* in_sizes, int n_in,
                              void* d_out, int out_size, void* d_ws, size_t ws_size,
                              hipStream_t stream) {
    (void)in_sizes; (void)n_in; (void)out_size; (void)ws_size;
    const float* x   = (const float*)d_in[0];
    const float* adj = (const float*)d_in[1];
    const float* eps = (const float*)d_in[2];
    const float* W1  = (const float*)d_in[3];
    const float* b1  = (const float*)d_in[4];
    const float* W2  = (const float*)d_in[5];
    const float* b2  = (const float*)d_in[6];
    float* out = (float*)d_out;

    char* ws = (char*)d_ws;
    f16* h_f16   = (f16*)(ws);                       // 16 MiB
    f16* xT      = (f16*)(ws + (16u << 20));         // 16 MiB (later reused by hidden)
    f16* hidden  = (f16*)(ws + (16u << 20));         // 32 MiB
    f16* W1T     = (f16*)(ws + (48u << 20));
    f16* W2T     = (f16*)(ws + (48u << 20) + 131072u * 2u * 2u);

    transpose_x_kernel<<<dim3(64, 4, 8), dim3(256), 0, stream>>>(x, xT);
    prep_weights_kernel<<<dim3(1024), dim3(256), 0, stream>>>(W1, W2, W1T, W2T);
    bmm_kernel<<<dim3(64, 8), dim3(256), 0, stream>>>(adj, xT, x, eps, h_f16);
    mlp_kernel<256, true, false><<<dim3(256, 4), dim3(256), 0, stream>>>(h_f16, W1T, b1, (void*)hidden, 512);
    mlp_kernel<512, false, true><<<dim3(256, 2), dim3(256), 0, stream>>>(hidden, W2T, b2, (void*)out, 256);
}